// Round 1
// baseline (430.624 us; speedup 1.0000x reference)
//
#include <hip/hip_runtime.h>
#include <math.h>

#define N_NODES 50000
#define N_EDGES 800000
#define N_GRAPHS 512
#define D 64
#define D_CLS 128

static inline int cdiv(int a, int b) { return (a + b - 1) / b; }

// ---------- CSR build ----------

__global__ void k_hist(const int* __restrict__ dst, int* __restrict__ cnt) {
    int e = blockIdx.x * blockDim.x + threadIdx.x;
    if (e < N_EDGES) atomicAdd(&cnt[dst[e]], 1);
}

__global__ void k_dis(const int* __restrict__ cnt, float* __restrict__ dis) {
    int i = blockIdx.x * blockDim.x + threadIdx.x;
    if (i < N_NODES) {
        float deg = (float)cnt[i] + 1.0f;   // +1 self loop
        dis[i] = 1.0f / sqrtf(deg);
    }
}

__global__ void k_scan1(const int* __restrict__ cnt, int* __restrict__ bsum) {
    __shared__ int s[256];
    int i = blockIdx.x * 256 + threadIdx.x;
    s[threadIdx.x] = (i < N_NODES) ? cnt[i] : 0;
    __syncthreads();
    for (int off = 128; off > 0; off >>= 1) {
        if (threadIdx.x < off) s[threadIdx.x] += s[threadIdx.x + off];
        __syncthreads();
    }
    if (threadIdx.x == 0) bsum[blockIdx.x] = s[0];
}

__global__ void k_scan2(int* bsum, int nb) {
    if (threadIdx.x == 0 && blockIdx.x == 0) {
        int acc = 0;
        for (int i = 0; i < nb; i++) { int v = bsum[i]; bsum[i] = acc; acc += v; }
    }
}

__global__ void k_scan3(const int* __restrict__ cnt, const int* __restrict__ bsum,
                        int* __restrict__ row_ptr) {
    __shared__ int s[256];
    int i = blockIdx.x * 256 + threadIdx.x;
    int v = (i < N_NODES) ? cnt[i] : 0;
    s[threadIdx.x] = v;
    __syncthreads();
    for (int off = 1; off < 256; off <<= 1) {
        int x = (threadIdx.x >= off) ? s[threadIdx.x - off] : 0;
        __syncthreads();
        s[threadIdx.x] += x;
        __syncthreads();
    }
    if (i < N_NODES) row_ptr[i] = bsum[blockIdx.x] + s[threadIdx.x] - v;
    if (i == 0) row_ptr[N_NODES] = N_EDGES;
}

__global__ void k_fill(const int* __restrict__ src, const int* __restrict__ dst,
                       const int* __restrict__ row_ptr, int* __restrict__ fill,
                       int* __restrict__ col) {
    int e = blockIdx.x * blockDim.x + threadIdx.x;
    if (e < N_EDGES) {
        int d = dst[e];
        int pos = row_ptr[d] + atomicAdd(&fill[d], 1);
        col[pos] = src[e];
    }
}

// ---------- GEMM (X @ W) with dis-row-scaling fused: G = dis ⊙ (X @ W) ----------

__global__ __launch_bounds__(256) void k_gemm_scale(
        const float* __restrict__ X, const float* __restrict__ W,
        const float* __restrict__ dis, float* __restrict__ G) {
    __shared__ float Xs[64 * 65];
    __shared__ float Ws[64 * 64];
    int n0 = blockIdx.x * 64;
    int t = threadIdx.x;

    // load W tile (64x64), 16 consecutive floats per thread
    {
        int base = t * 16;
        const float4* wsrc = (const float4*)(W + base);
        float4* wdst = (float4*)(Ws + base);
        wdst[0] = wsrc[0]; wdst[1] = wsrc[1]; wdst[2] = wsrc[2]; wdst[3] = wsrc[3];
    }
    // load X tile (64 rows x 64 cols), padded LDS stride 65
    {
        int row = t >> 2;
        int c0 = (t & 3) * 16;
        int grow = n0 + row;
        if (grow < N_NODES) {
            const float* xp = X + (size_t)grow * D + c0;
            #pragma unroll
            for (int j = 0; j < 16; j++) Xs[row * 65 + c0 + j] = xp[j];
        } else {
            #pragma unroll
            for (int j = 0; j < 16; j++) Xs[row * 65 + c0 + j] = 0.f;
        }
    }
    __syncthreads();

    int tc = t & 15, tr = t >> 4;
    int r0 = tr * 4, c0 = tc * 4;
    float acc[4][4] = {};
    #pragma unroll 4
    for (int k = 0; k < 64; k++) {
        float4 wv = *(const float4*)&Ws[k * 64 + c0];
        #pragma unroll
        for (int i = 0; i < 4; i++) {
            float xv = Xs[(r0 + i) * 65 + k];
            acc[i][0] = fmaf(xv, wv.x, acc[i][0]);
            acc[i][1] = fmaf(xv, wv.y, acc[i][1]);
            acc[i][2] = fmaf(xv, wv.z, acc[i][2]);
            acc[i][3] = fmaf(xv, wv.w, acc[i][3]);
        }
    }
    #pragma unroll
    for (int i = 0; i < 4; i++) {
        int grow = n0 + r0 + i;
        if (grow < N_NODES) {
            float dsc = dis[grow];
            float4 o;
            o.x = acc[i][0] * dsc; o.y = acc[i][1] * dsc;
            o.z = acc[i][2] * dsc; o.w = acc[i][3] * dsc;
            *(float4*)&G[(size_t)grow * D + c0] = o;
        }
    }
}

// ---------- aggregation: Out_n = dis_n * (G_n + sum_{src in in(n)} G_src) + b ----------

__global__ __launch_bounds__(256) void k_agg(
        const float* __restrict__ G, const int* __restrict__ row_ptr,
        const int* __restrict__ col, const float* __restrict__ dis,
        const float* __restrict__ bias, float* __restrict__ Out) {
    int n = blockIdx.x * 4 + (threadIdx.x >> 6);
    int c = threadIdx.x & 63;
    if (n >= N_NODES) return;
    int s = row_ptr[n], e = row_ptr[n + 1];
    float acc = G[(size_t)n * D + c];
    for (int i = s; i < e; i++) {
        int sc = col[i];
        acc += G[(size_t)sc * D + c];
    }
    Out[(size_t)n * D + c] = dis[n] * acc + bias[c];
}

// ---------- pooling ----------

__global__ void k_bounds(const int* __restrict__ batch, int* __restrict__ start) {
    int g = blockIdx.x * blockDim.x + threadIdx.x;
    if (g <= N_GRAPHS) {
        int lo = 0, hi = N_NODES;
        while (lo < hi) {
            int mid = (lo + hi) >> 1;
            if (batch[mid] < g) lo = mid + 1; else hi = mid;
        }
        start[g] = lo;
    }
}

__global__ __launch_bounds__(256) void k_pool(
        const float* __restrict__ H, const int* __restrict__ start,
        float* __restrict__ P) {
    int g = blockIdx.x * 4 + (threadIdx.x >> 6);
    int c = threadIdx.x & 63;
    if (g >= N_GRAPHS) return;
    int s = start[g], e = start[g + 1];
    float acc = 0.f;
    for (int r = s; r < e; r++) acc += H[(size_t)r * D + c];
    int cntr = e - s;
    P[g * D + c] = acc / (float)(cntr > 0 ? cntr : 1);
}

// ---------- classifier MLP ----------

__global__ __launch_bounds__(128) void k_mlp(
        const float* __restrict__ P,
        const float* __restrict__ w1, const float* __restrict__ b1,
        const float* __restrict__ w2, const float* __restrict__ b2,
        const float* __restrict__ fcw, const float* __restrict__ fcb,
        float* __restrict__ out) {
    __shared__ float ps[64];
    __shared__ float red[128];
    int g = blockIdx.x, t = threadIdx.x;
    if (t < 64) ps[t] = P[g * D + t];
    __syncthreads();
    float acc = b1[t];
    #pragma unroll
    for (int k = 0; k < 64; k++) acc = fmaf(ps[k], w1[k * D_CLS + t], acc);
    red[t] = acc * w2[t];
    __syncthreads();
    for (int s2 = 64; s2 > 0; s2 >>= 1) {
        if (t < s2) red[t] += red[t + s2];
        __syncthreads();
    }
    if (t == 0) {
        float o = red[0] + b2[0];
        o = fmaf(o, fcw[0], fcb[0]);
        out[g] = (o >= 0.f) ? o : 0.01f * o;
    }
}

// ---------- launch ----------

extern "C" void kernel_launch(void* const* d_in, const int* in_sizes, int n_in,
                              void* d_out, int out_size, void* d_ws, size_t ws_size,
                              hipStream_t stream) {
    const float* x   = (const float*)d_in[0];
    const float* W0  = (const float*)d_in[1];
    const float* b0  = (const float*)d_in[2];
    const float* W1  = (const float*)d_in[3];
    const float* b1  = (const float*)d_in[4];
    const float* W2  = (const float*)d_in[5];
    const float* b2  = (const float*)d_in[6];
    const float* l1w = (const float*)d_in[7];
    const float* l1b = (const float*)d_in[8];
    const float* l2w = (const float*)d_in[9];
    const float* l2b = (const float*)d_in[10];
    const float* fcw = (const float*)d_in[11];
    const float* fcb = (const float*)d_in[12];
    const int* eidx  = (const int*)d_in[13];
    const int* batch = (const int*)d_in[14];
    const int* src = eidx;
    const int* dst = eidx + N_EDGES;

    char* ws = (char*)d_ws;
    size_t off = 0;
    auto alloc = [&](size_t bytes) -> void* {
        off = (off + 255) & ~(size_t)255;
        void* p = ws + off;
        off += bytes;
        return p;
    };

    int*   row_ptr = (int*)  alloc((N_NODES + 1) * sizeof(int));
    int*   cnt     = (int*)  alloc(N_NODES * sizeof(int));
    int*   fill    = (int*)  alloc(N_NODES * sizeof(int));
    int*   bsum    = (int*)  alloc(256 * sizeof(int));
    int*   col     = (int*)  alloc(N_EDGES * sizeof(int));
    float* dis     = (float*)alloc(N_NODES * sizeof(float));
    int*   start   = (int*)  alloc((N_GRAPHS + 1) * sizeof(int));
    float* bufA    = (float*)alloc((size_t)N_NODES * D * sizeof(float));
    float* bufB    = (float*)alloc((size_t)N_NODES * D * sizeof(float));
    float* bufC    = (float*)alloc((size_t)N_NODES * D * sizeof(float));
    float* pooled  = (float*)alloc((size_t)N_GRAPHS * D * sizeof(float));

    const int nbScan = cdiv(N_NODES, 256);   // 196
    const int nbE    = cdiv(N_EDGES, 256);   // 3125

    hipMemsetAsync(cnt,  0, N_NODES * sizeof(int), stream);
    hipMemsetAsync(fill, 0, N_NODES * sizeof(int), stream);

    k_hist<<<nbE, 256, 0, stream>>>(dst, cnt);
    k_dis<<<nbScan, 256, 0, stream>>>(cnt, dis);
    k_scan1<<<nbScan, 256, 0, stream>>>(cnt, bsum);
    k_scan2<<<1, 64, 0, stream>>>(bsum, nbScan);
    k_scan3<<<nbScan, 256, 0, stream>>>(cnt, bsum, row_ptr);
    k_fill<<<nbE, 256, 0, stream>>>(src, dst, row_ptr, fill, col);

    const int nbGemm = cdiv(N_NODES, 64);    // 782
    const int nbAgg  = cdiv(N_NODES, 4);     // 12500

    // layer 0: x -> B
    k_gemm_scale<<<nbGemm, 256, 0, stream>>>(x, W0, dis, bufA);
    k_agg<<<nbAgg, 256, 0, stream>>>(bufA, row_ptr, col, dis, b0, bufB);
    // layer 1: B -> C
    k_gemm_scale<<<nbGemm, 256, 0, stream>>>(bufB, W1, dis, bufA);
    k_agg<<<nbAgg, 256, 0, stream>>>(bufA, row_ptr, col, dis, b1, bufC);
    // layer 2: C -> B
    k_gemm_scale<<<nbGemm, 256, 0, stream>>>(bufC, W2, dis, bufA);
    k_agg<<<nbAgg, 256, 0, stream>>>(bufA, row_ptr, col, dis, b2, bufB);

    k_bounds<<<cdiv(N_GRAPHS + 1, 256), 256, 0, stream>>>(batch, start);
    k_pool<<<cdiv(N_GRAPHS, 4), 256, 0, stream>>>(bufB, start, pooled);
    k_mlp<<<N_GRAPHS, 128, 0, stream>>>(pooled, l1w, l1b, l2w, l2b, fcw, fcb,
                                        (float*)d_out);
}

// Round 2
// 274.152 us; speedup vs baseline: 1.5707x; 1.5707x over previous
//
#include <hip/hip_runtime.h>
#include <math.h>

#define N_NODES 50000
#define N_EDGES 800000
#define N_GRAPHS 512
#define D 64
#define D_CLS 128

static inline int cdiv(int a, int b) { return (a + b - 1) / b; }

// ---------- CSR build ----------

__global__ void k_hist(const int* __restrict__ dst, int* __restrict__ cnt) {
    int e = blockIdx.x * blockDim.x + threadIdx.x;
    if (e < N_EDGES) atomicAdd(&cnt[dst[e]], 1);
}

__global__ void k_dis(const int* __restrict__ cnt, float* __restrict__ dis) {
    int i = blockIdx.x * blockDim.x + threadIdx.x;
    if (i < N_NODES) {
        float deg = (float)cnt[i] + 1.0f;   // +1 self loop
        dis[i] = 1.0f / sqrtf(deg);
    }
}

__global__ void k_scan1(const int* __restrict__ cnt, int* __restrict__ bsum) {
    __shared__ int s[256];
    int i = blockIdx.x * 256 + threadIdx.x;
    s[threadIdx.x] = (i < N_NODES) ? cnt[i] : 0;
    __syncthreads();
    for (int off = 128; off > 0; off >>= 1) {
        if (threadIdx.x < off) s[threadIdx.x] += s[threadIdx.x + off];
        __syncthreads();
    }
    if (threadIdx.x == 0) bsum[blockIdx.x] = s[0];
}

__global__ void k_scan2(int* bsum, int nb) {
    if (threadIdx.x == 0 && blockIdx.x == 0) {
        int acc = 0;
        for (int i = 0; i < nb; i++) { int v = bsum[i]; bsum[i] = acc; acc += v; }
    }
}

__global__ void k_scan3(const int* __restrict__ cnt, const int* __restrict__ bsum,
                        int* __restrict__ row_ptr) {
    __shared__ int s[256];
    int i = blockIdx.x * 256 + threadIdx.x;
    int v = (i < N_NODES) ? cnt[i] : 0;
    s[threadIdx.x] = v;
    __syncthreads();
    for (int off = 1; off < 256; off <<= 1) {
        int x = (threadIdx.x >= off) ? s[threadIdx.x - off] : 0;
        __syncthreads();
        s[threadIdx.x] += x;
        __syncthreads();
    }
    if (i < N_NODES) row_ptr[i] = bsum[blockIdx.x] + s[threadIdx.x] - v;
    if (i == 0) row_ptr[N_NODES] = N_EDGES;
}

// consumes cnt (counts from k_hist) via atomicSub -> no separate fill buffer
__global__ void k_fill(const int* __restrict__ src, const int* __restrict__ dst,
                       const int* __restrict__ row_ptr, int* __restrict__ cnt,
                       int* __restrict__ col) {
    int e = blockIdx.x * blockDim.x + threadIdx.x;
    if (e < N_EDGES) {
        int d = dst[e];
        int pos = row_ptr[d] + atomicSub(&cnt[d], 1) - 1;
        col[pos] = src[e];
    }
}

// ---------- GEMM (X @ W) with dis-row-scaling fused: G = dis ⊙ (X @ W) ----------

#define XS_STRIDE 68   // 64 + 4 pad, keeps 16B alignment for float4 LDS ops

__global__ __launch_bounds__(256) void k_gemm_scale(
        const float* __restrict__ X, const float* __restrict__ W,
        const float* __restrict__ dis, float* __restrict__ G) {
    __shared__ float Xs[64 * XS_STRIDE];
    __shared__ float Ws[64 * 64];
    int n0 = blockIdx.x * 64;
    int t = threadIdx.x;

    // load W tile (64x64), 16 consecutive floats per thread
    {
        int base = t * 16;
        const float4* wsrc = (const float4*)(W + base);
        float4* wdst = (float4*)(Ws + base);
        wdst[0] = wsrc[0]; wdst[1] = wsrc[1]; wdst[2] = wsrc[2]; wdst[3] = wsrc[3];
    }
    // load X tile (64 rows x 64 cols) with float4
    {
        int row = t >> 2;
        int c0 = (t & 3) * 16;
        int grow = n0 + row;
        float4* xd = (float4*)(Xs + row * XS_STRIDE + c0);
        if (grow < N_NODES) {
            const float4* xp = (const float4*)(X + (size_t)grow * D + c0);
            xd[0] = xp[0]; xd[1] = xp[1]; xd[2] = xp[2]; xd[3] = xp[3];
        } else {
            float4 z = {0.f, 0.f, 0.f, 0.f};
            xd[0] = z; xd[1] = z; xd[2] = z; xd[3] = z;
        }
    }
    __syncthreads();

    int tc = t & 15, tr = t >> 4;
    int r0 = tr * 4, c0 = tc * 4;
    float acc[4][4] = {};
    #pragma unroll 4
    for (int k = 0; k < 64; k++) {
        float4 wv = *(const float4*)&Ws[k * 64 + c0];
        #pragma unroll
        for (int i = 0; i < 4; i++) {
            float xv = Xs[(r0 + i) * XS_STRIDE + k];
            acc[i][0] = fmaf(xv, wv.x, acc[i][0]);
            acc[i][1] = fmaf(xv, wv.y, acc[i][1]);
            acc[i][2] = fmaf(xv, wv.z, acc[i][2]);
            acc[i][3] = fmaf(xv, wv.w, acc[i][3]);
        }
    }
    #pragma unroll
    for (int i = 0; i < 4; i++) {
        int grow = n0 + r0 + i;
        if (grow < N_NODES) {
            float dsc = dis[grow];
            float4 o;
            o.x = acc[i][0] * dsc; o.y = acc[i][1] * dsc;
            o.z = acc[i][2] * dsc; o.w = acc[i][3] * dsc;
            *(float4*)&G[(size_t)grow * D + c0] = o;
        }
    }
}

// ---------- aggregation: Out_n = dis_n * (G_n + sum_{src in in(n)} G_src) + b ----
// wave = node; lanes = 4 edge-slots x 16 feature-groups (float4 each)
// -> 4 concurrent row gathers per iteration, unrolled x2 -> up to 8 in flight.

__global__ __launch_bounds__(256) void k_agg(
        const float* __restrict__ G, const int* __restrict__ row_ptr,
        const int* __restrict__ col, const float* __restrict__ dis,
        const float* __restrict__ bias, float* __restrict__ Out) {
    int n = blockIdx.x * 4 + (threadIdx.x >> 6);
    if (n >= N_NODES) return;
    int lane = threadIdx.x & 63;
    int es  = lane >> 4;          // edge slot 0..3
    int fg4 = (lane & 15) * 4;    // feature offset

    int s = row_ptr[n], e = row_ptr[n + 1];
    float4 acc = {0.f, 0.f, 0.f, 0.f};

    int i = s + es;
    while (i + 4 < e) {           // both i and i+4 valid
        int c0 = col[i];
        int c1 = col[i + 4];
        float4 g0 = *(const float4*)(G + (size_t)c0 * D + fg4);
        float4 g1 = *(const float4*)(G + (size_t)c1 * D + fg4);
        acc.x += g0.x; acc.y += g0.y; acc.z += g0.z; acc.w += g0.w;
        acc.x += g1.x; acc.y += g1.y; acc.z += g1.z; acc.w += g1.w;
        i += 8;
    }
    if (i < e) {
        int c0 = col[i];
        float4 g0 = *(const float4*)(G + (size_t)c0 * D + fg4);
        acc.x += g0.x; acc.y += g0.y; acc.z += g0.z; acc.w += g0.w;
    }

    // fold the 4 edge slots
    #pragma unroll
    for (int m = 16; m < 64; m <<= 1) {
        acc.x += __shfl_xor(acc.x, m, 64);
        acc.y += __shfl_xor(acc.y, m, 64);
        acc.z += __shfl_xor(acc.z, m, 64);
        acc.w += __shfl_xor(acc.w, m, 64);
    }

    float4 self = *(const float4*)(G + (size_t)n * D + fg4);
    float4 bv   = *(const float4*)(bias + fg4);
    float dsc = dis[n];
    float4 o;
    o.x = fmaf(dsc, acc.x + self.x, bv.x);
    o.y = fmaf(dsc, acc.y + self.y, bv.y);
    o.z = fmaf(dsc, acc.z + self.z, bv.z);
    o.w = fmaf(dsc, acc.w + self.w, bv.w);
    if (es == 0) *(float4*)(Out + (size_t)n * D + fg4) = o;
}

// ---------- pooling ----------

__global__ void k_bounds(const int* __restrict__ batch, int* __restrict__ start) {
    int g = blockIdx.x * blockDim.x + threadIdx.x;
    if (g <= N_GRAPHS) {
        int lo = 0, hi = N_NODES;
        while (lo < hi) {
            int mid = (lo + hi) >> 1;
            if (batch[mid] < g) lo = mid + 1; else hi = mid;
        }
        start[g] = lo;
    }
}

__global__ __launch_bounds__(256) void k_pool(
        const float* __restrict__ H, const int* __restrict__ start,
        float* __restrict__ P) {
    int g = blockIdx.x * 4 + (threadIdx.x >> 6);
    if (g >= N_GRAPHS) return;
    int lane = threadIdx.x & 63;
    int es  = lane >> 4;
    int fg4 = (lane & 15) * 4;
    int s = start[g], e = start[g + 1];
    float4 acc = {0.f, 0.f, 0.f, 0.f};
    for (int r = s + es; r < e; r += 4) {
        float4 h = *(const float4*)(H + (size_t)r * D + fg4);
        acc.x += h.x; acc.y += h.y; acc.z += h.z; acc.w += h.w;
    }
    #pragma unroll
    for (int m = 16; m < 64; m <<= 1) {
        acc.x += __shfl_xor(acc.x, m, 64);
        acc.y += __shfl_xor(acc.y, m, 64);
        acc.z += __shfl_xor(acc.z, m, 64);
        acc.w += __shfl_xor(acc.w, m, 64);
    }
    int cntr = e - s;
    float inv = 1.0f / (float)(cntr > 0 ? cntr : 1);
    if (es == 0) {
        float4 o;
        o.x = acc.x * inv; o.y = acc.y * inv; o.z = acc.z * inv; o.w = acc.w * inv;
        *(float4*)(P + g * D + fg4) = o;
    }
}

// ---------- classifier MLP ----------

__global__ __launch_bounds__(128) void k_mlp(
        const float* __restrict__ P,
        const float* __restrict__ w1, const float* __restrict__ b1,
        const float* __restrict__ w2, const float* __restrict__ b2,
        const float* __restrict__ fcw, const float* __restrict__ fcb,
        float* __restrict__ out) {
    __shared__ float ps[64];
    __shared__ float red[128];
    int g = blockIdx.x, t = threadIdx.x;
    if (t < 64) ps[t] = P[g * D + t];
    __syncthreads();
    float acc = b1[t];
    #pragma unroll
    for (int k = 0; k < 64; k++) acc = fmaf(ps[k], w1[k * D_CLS + t], acc);
    red[t] = acc * w2[t];
    __syncthreads();
    for (int s2 = 64; s2 > 0; s2 >>= 1) {
        if (t < s2) red[t] += red[t + s2];
        __syncthreads();
    }
    if (t == 0) {
        float o = red[0] + b2[0];
        o = fmaf(o, fcw[0], fcb[0]);
        out[g] = (o >= 0.f) ? o : 0.01f * o;
    }
}

// ---------- launch ----------

extern "C" void kernel_launch(void* const* d_in, const int* in_sizes, int n_in,
                              void* d_out, int out_size, void* d_ws, size_t ws_size,
                              hipStream_t stream) {
    const float* x   = (const float*)d_in[0];
    const float* W0  = (const float*)d_in[1];
    const float* b0  = (const float*)d_in[2];
    const float* W1  = (const float*)d_in[3];
    const float* b1  = (const float*)d_in[4];
    const float* W2  = (const float*)d_in[5];
    const float* b2  = (const float*)d_in[6];
    const float* l1w = (const float*)d_in[7];
    const float* l1b = (const float*)d_in[8];
    const float* l2w = (const float*)d_in[9];
    const float* l2b = (const float*)d_in[10];
    const float* fcw = (const float*)d_in[11];
    const float* fcb = (const float*)d_in[12];
    const int* eidx  = (const int*)d_in[13];
    const int* batch = (const int*)d_in[14];
    const int* src = eidx;
    const int* dst = eidx + N_EDGES;

    char* ws = (char*)d_ws;
    size_t off = 0;
    auto alloc = [&](size_t bytes) -> void* {
        off = (off + 255) & ~(size_t)255;
        void* p = ws + off;
        off += bytes;
        return p;
    };

    int*   row_ptr = (int*)  alloc((N_NODES + 1) * sizeof(int));
    int*   cnt     = (int*)  alloc(N_NODES * sizeof(int));
    int*   bsum    = (int*)  alloc(256 * sizeof(int));
    int*   col     = (int*)  alloc(N_EDGES * sizeof(int));
    float* dis     = (float*)alloc(N_NODES * sizeof(float));
    int*   start   = (int*)  alloc((N_GRAPHS + 1) * sizeof(int));
    float* bufA    = (float*)alloc((size_t)N_NODES * D * sizeof(float));
    float* bufB    = (float*)alloc((size_t)N_NODES * D * sizeof(float));
    float* bufC    = (float*)alloc((size_t)N_NODES * D * sizeof(float));
    float* pooled  = (float*)alloc((size_t)N_GRAPHS * D * sizeof(float));

    const int nbScan = cdiv(N_NODES, 256);   // 196
    const int nbE    = cdiv(N_EDGES, 256);   // 3125

    hipMemsetAsync(cnt, 0, N_NODES * sizeof(int), stream);

    k_hist<<<nbE, 256, 0, stream>>>(dst, cnt);
    k_dis<<<nbScan, 256, 0, stream>>>(cnt, dis);
    k_scan1<<<nbScan, 256, 0, stream>>>(cnt, bsum);
    k_scan2<<<1, 64, 0, stream>>>(bsum, nbScan);
    k_scan3<<<nbScan, 256, 0, stream>>>(cnt, bsum, row_ptr);
    k_fill<<<nbE, 256, 0, stream>>>(src, dst, row_ptr, cnt, col);

    const int nbGemm = cdiv(N_NODES, 64);    // 782
    const int nbAgg  = cdiv(N_NODES, 4);     // 12500

    // layer 0: x -> B
    k_gemm_scale<<<nbGemm, 256, 0, stream>>>(x, W0, dis, bufA);
    k_agg<<<nbAgg, 256, 0, stream>>>(bufA, row_ptr, col, dis, b0, bufB);
    // layer 1: B -> C
    k_gemm_scale<<<nbGemm, 256, 0, stream>>>(bufB, W1, dis, bufA);
    k_agg<<<nbAgg, 256, 0, stream>>>(bufA, row_ptr, col, dis, b1, bufC);
    // layer 2: C -> B
    k_gemm_scale<<<nbGemm, 256, 0, stream>>>(bufC, W2, dis, bufA);
    k_agg<<<nbAgg, 256, 0, stream>>>(bufA, row_ptr, col, dis, b2, bufB);

    k_bounds<<<cdiv(N_GRAPHS + 1, 256), 256, 0, stream>>>(batch, start);
    k_pool<<<cdiv(N_GRAPHS, 4), 256, 0, stream>>>(bufB, start, pooled);
    k_mlp<<<N_GRAPHS, 128, 0, stream>>>(pooled, l1w, l1b, l2w, l2b, fcw, fcb,
                                        (float*)d_out);
}